// Round 4
// baseline (912.282 us; speedup 1.0000x reference)
//
#include <hip/hip_runtime.h>

// 2-layer GCN + mean-pool + linear head for MI355X (gfx950).
// R1: k_fused as node-tiled register-blocked double GEMM (weight reuse).
// R2: atomic scatters -> CSR counting sort + gather; gather2 fused with pool+head.
// R3: k_fused2 hidden-dim split into two 128-col passes to halve LDS
//     (46.1 -> 27.6 KB): occupancy was 31.7% (2-3 blocks/CU) and VALUBusy 30%
//     because W2 L2-latency couldn't be hidden by 2.5 waves/SIMD.

constexpr int NPG = 128;   // nodes per graph
constexpr int F0  = 64;    // in_feats
constexpr int F1  = 256;   // hidden
constexpr int F2  = 128;   // readout
constexpr int BM  = 32;    // nodes per fused block
constexpr int LDA = BM + 4;
constexpr int FH  = 128;   // hidden-split width

constexpr int SC_T = 256;   // scan threads/block
constexpr int SC_E = 1024;  // scan elems/block

__device__ __forceinline__ float leaky(float x) {
    return (x >= 0.f) ? x : 0.01f * x;
}

// ---- CSR build -------------------------------------------------------------

__global__ void k_hist(const int* __restrict__ src, const int* __restrict__ dst,
                       int* __restrict__ cnt_src, int* __restrict__ cnt_dst, unsigned E) {
    unsigned e = blockIdx.x * 256u + threadIdx.x;
    if (e < E) {
        atomicAdd(&cnt_src[src[e]], 1);
        atomicAdd(&cnt_dst[dst[e]], 1);
    }
}

__global__ void k_finalize_deg(const int* __restrict__ cnt_src, const int* __restrict__ cnt_dst,
                               float* __restrict__ dinv_out, float* __restrict__ dinv_in, int N) {
    int i = blockIdx.x * blockDim.x + threadIdx.x;
    if (i < N) {
        dinv_out[i] = rsqrtf((float)max(cnt_src[i], 1));
        dinv_in[i]  = rsqrtf((float)max(cnt_dst[i], 1));
    }
}

// local exclusive scan of 1024 ints per block; block total -> bsum
__global__ void k_scan_local(const int* __restrict__ cnt, int* __restrict__ part,
                             int* __restrict__ bsum, int N) {
    __shared__ int s[SC_T];
    int b = blockIdx.x, t = threadIdx.x;
    int base = b * SC_E + t * 4;
    int v0 = (base + 0 < N) ? cnt[base + 0] : 0;
    int v1 = (base + 1 < N) ? cnt[base + 1] : 0;
    int v2 = (base + 2 < N) ? cnt[base + 2] : 0;
    int v3 = (base + 3 < N) ? cnt[base + 3] : 0;
    int s0 = v0, s1 = s0 + v1, s2 = s1 + v2, s3 = s2 + v3;
    s[t] = s3;
    __syncthreads();
    for (int off = 1; off < SC_T; off <<= 1) {
        int x = (t >= off) ? s[t - off] : 0;
        __syncthreads();
        s[t] += x;
        __syncthreads();
    }
    int excl = t ? s[t - 1] : 0;
    if (base + 0 < N) part[base + 0] = excl;
    if (base + 1 < N) part[base + 1] = excl + s0;
    if (base + 2 < N) part[base + 2] = excl + s1;
    if (base + 3 < N) part[base + 3] = excl + s2;
    if (t == SC_T - 1) bsum[b] = s[t];
}

// single-block exclusive scan of block sums (nb <= 256)
__global__ void k_scan_blocks(int* __restrict__ bsum, int nb) {
    __shared__ int s[256];
    int t = threadIdx.x;
    s[t] = (t < nb) ? bsum[t] : 0;
    __syncthreads();
    for (int off = 1; off < 256; off <<= 1) {
        int x = (t >= off) ? s[t - off] : 0;
        __syncthreads();
        s[t] += x;
        __syncthreads();
    }
    if (t < nb) bsum[t] = t ? s[t - 1] : 0;
}

__global__ void k_scan_add(int* __restrict__ rowptr, const int* __restrict__ bsum,
                           int* __restrict__ cursor, int N, int E) {
    int b = blockIdx.x, t = threadIdx.x;
    int base = b * SC_E + t * 4;
    int off = bsum[b];
#pragma unroll
    for (int j = 0; j < 4; ++j) {
        if (base + j < N) {
            int r = rowptr[base + j] + off;
            rowptr[base + j] = r;
            cursor[base + j] = r;
        }
    }
    if (b == gridDim.x - 1 && t == SC_T - 1) rowptr[N] = E;
}

__global__ void k_fill(const int* __restrict__ src, const int* __restrict__ dst,
                       const float* __restrict__ we, int* __restrict__ cursor,
                       int2* __restrict__ sorted, unsigned E) {
    unsigned e = blockIdx.x * 256u + threadIdx.x;
    if (e < E) {
        int pos = atomicAdd(&cursor[dst[e]], 1);
        sorted[pos] = make_int2(src[e], __float_as_int(we[e]));
    }
}

// ---- layer 1 gather: agg1[n] = dinv_in[n] * sum_e feats[src]*(w*dinv_out[src])
__global__ void __launch_bounds__(256) k_gather1(
        const float* __restrict__ feats, const int* __restrict__ rowptr,
        const int2* __restrict__ sorted, const float* __restrict__ dinv_out,
        const float* __restrict__ dinv_in, float* __restrict__ agg1, int N) {
    int gid = blockIdx.x * 256 + threadIdx.x;
    int n = gid >> 6;
    int d = gid & 63;
    if (n >= N) return;
    int e0 = rowptr[n], e1 = rowptr[n + 1];
    float acc = 0.f;
    for (int e = e0; e < e1; ++e) {
        int2 p = sorted[e];
        float w = __int_as_float(p.y) * dinv_out[p.x];
        acc = fmaf(feats[(size_t)p.x * F0 + d], w, acc);
    }
    agg1[(size_t)n * F0 + d] = acc * dinv_in[n];
}

// ---- fused: x2 = (leaky(agg1 @ W1) * dinv_out) @ W2   (agg1 pre-scaled)
// Hidden dim processed in two 128-col passes; acc2 persists across passes.
// LDS: aT 64x36 (9.2 KB) + hT 128x36 (18.4 KB) = 27.6 KB -> 5 blocks/CU.
__global__ void __launch_bounds__(256, 5) k_fused2(
        const float* __restrict__ agg1,
        const float* __restrict__ dinv_out,
        const float* __restrict__ W1,   // [64][256]
        const float* __restrict__ W2,   // [256][128]
        float* __restrict__ x2) {
    __shared__ float aT[F0][LDA];
    __shared__ float hT[FH][LDA];
    const int t = threadIdx.x;
    const int base = blockIdx.x * BM;

    // ---- load A tile (32 nodes x 64 feats), transpose into LDS
    {
        const int nn = t >> 3;
        const int f0 = (t & 7) * 8;
        const float4* p = (const float4*)(agg1 + (size_t)(base + nn) * F0 + f0);
        float4 v0 = p[0], v1 = p[1];
        float v[8] = {v0.x, v0.y, v0.z, v0.w, v1.x, v1.y, v1.z, v1.w};
#pragma unroll
        for (int j = 0; j < 8; ++j) {
            int f = f0 + j;
            aT[f][nn ^ (((f >> 3) & 7) << 2)] = v[j];
        }
    }

    // phase-1 mapping: 32 col-groups x 4 cols, 8 node-groups x 4 nodes
    const int c0 = (t & 31) * 4;
    const int n0 = (t >> 5) * 4;
    // phase-2 mapping: 16 col-groups x 8 cols, 16 node-groups x 2 nodes
    const int c2 = (t & 15) * 8;
    const int n2 = (t >> 4) * 2;

    float dsc[4];
#pragma unroll
    for (int i = 0; i < 4; ++i) dsc[i] = dinv_out[base + n0 + i];

    float acc2[2][8];
#pragma unroll
    for (int i = 0; i < 2; ++i)
#pragma unroll
        for (int j = 0; j < 8; ++j) acc2[i][j] = 0.f;

    __syncthreads();

#pragma unroll
    for (int half = 0; half < 2; ++half) {
        // ---- phase 1: H[:, half*128 + (0..127)] = leaky(A @ W1) * dout
        float acc[4][4];
#pragma unroll
        for (int i = 0; i < 4; ++i)
#pragma unroll
            for (int j = 0; j < 4; ++j) acc[i][j] = 0.f;

#pragma unroll 8
        for (int k = 0; k < F0; ++k) {
            const float4 a = *(const float4*)&aT[k][n0 ^ (((k >> 3) & 7) << 2)];
            const float4 w = *(const float4*)&W1[k * F1 + half * FH + c0];
            const float an[4] = {a.x, a.y, a.z, a.w};
            const float wc[4] = {w.x, w.y, w.z, w.w};
#pragma unroll
            for (int i = 0; i < 4; ++i)
#pragma unroll
                for (int j = 0; j < 4; ++j)
                    acc[i][j] = fmaf(an[i], wc[j], acc[i][j]);
        }

#pragma unroll
        for (int j = 0; j < 4; ++j) {
            const int lc = c0 + j;
            float4 v;
            v.x = leaky(acc[0][j]) * dsc[0];
            v.y = leaky(acc[1][j]) * dsc[1];
            v.z = leaky(acc[2][j]) * dsc[2];
            v.w = leaky(acc[3][j]) * dsc[3];
            *(float4*)&hT[lc][n0 ^ (((lc >> 3) & 7) << 2)] = v;
        }
        __syncthreads();

        // ---- phase 2: acc2 += H[:, half-cols] @ W2[half-rows, :]
#pragma unroll 8
        for (int lc = 0; lc < FH; ++lc) {
            const int k = half * FH + lc;
            const float2 h = *(const float2*)&hT[lc][n2 ^ (((lc >> 3) & 7) << 2)];
            const float4 w0 = *(const float4*)&W2[k * F2 + c2];
            const float4 w1 = *(const float4*)&W2[k * F2 + c2 + 4];
            const float hn[2] = {h.x, h.y};
            const float wc[8] = {w0.x, w0.y, w0.z, w0.w, w1.x, w1.y, w1.z, w1.w};
#pragma unroll
            for (int i = 0; i < 2; ++i)
#pragma unroll
                for (int j = 0; j < 8; ++j)
                    acc2[i][j] = fmaf(hn[i], wc[j], acc2[i][j]);
        }
        __syncthreads();   // hT consumed before next half overwrites it
    }

#pragma unroll
    for (int i = 0; i < 2; ++i) {
        float* dstp = x2 + (size_t)(base + n2 + i) * F2 + c2;
        *(float4*)dstp       = make_float4(acc2[i][0], acc2[i][1], acc2[i][2], acc2[i][3]);
        *(float4*)(dstp + 4) = make_float4(acc2[i][4], acc2[i][5], acc2[i][6], acc2[i][7]);
    }
}

// ---- layer 2 gather + scale + leaky + mean-pool + head, one block per graph
__global__ void __launch_bounds__(256) k_gather2_pool(
        const float* __restrict__ x2, const int* __restrict__ rowptr,
        const int2* __restrict__ sorted, const float* __restrict__ dinv_in,
        const float* __restrict__ Wlin,   // [128][64]
        const float* __restrict__ Wcls,   // [64][16]
        float* __restrict__ out) {
    int g = blockIdx.x;
    int t = threadIdx.x;
    int d = t & 127;
    int half = t >> 7;           // 2 nodes in flight
    __shared__ float pl[2][F2];
    __shared__ float p[F2];
    __shared__ float tj[64];

    float pool = 0.f;
    int nbase = g * NPG;
    for (int i = 0; i < NPG; i += 2) {
        int n = nbase + i + half;
        int e0 = rowptr[n], e1 = rowptr[n + 1];
        float acc = 0.f;
        for (int e = e0; e < e1; ++e) {
            int2 pe = sorted[e];
            acc = fmaf(x2[(size_t)pe.x * F2 + d], __int_as_float(pe.y), acc);
        }
        pool += leaky(acc * dinv_in[n]);
    }
    pl[half][d] = pool;
    __syncthreads();
    if (t < F2) p[t] = (pl[0][t] + pl[1][t]) * (1.0f / NPG);
    __syncthreads();
    if (t < 64) {
        float s = 0.f;
#pragma unroll
        for (int k = 0; k < F2; ++k) s = fmaf(p[k], Wlin[k * 64 + t], s);
        tj[t] = s;
    }
    __syncthreads();
    if (t < 16) {
        float s = 0.f;
#pragma unroll
        for (int j = 0; j < 64; ++j) s = fmaf(tj[j], Wcls[j * 16 + t], s);
        out[g * 16 + t] = s;
    }
}

extern "C" void kernel_launch(void* const* d_in, const int* in_sizes, int n_in,
                              void* d_out, int out_size, void* d_ws, size_t ws_size,
                              hipStream_t stream) {
    const float* feats = (const float*)d_in[0];
    const float* we    = (const float*)d_in[1];
    const float* W1    = (const float*)d_in[2];
    const float* W2    = (const float*)d_in[3];
    const float* Wlin  = (const float*)d_in[4];
    const float* Wcls  = (const float*)d_in[5];
    const int*   src   = (const int*)d_in[6];
    const int*   dst   = (const int*)d_in[7];

    const int N = in_sizes[0] / F0;            // 131072
    const unsigned E = (unsigned)in_sizes[1];  // 1048576
    const int G = N / NPG;                     // 1024

    float* out = (float*)d_out;

    // workspace layout (4-byte units)
    int* ws_i = (int*)d_ws;
    size_t o = 0;
    int* cnt_src = ws_i + o; o += N;
    int* cnt_dst = ws_i + o; o += N;
    int* rowptr  = ws_i + o; o += (size_t)N + 64;
    int* cursor  = ws_i + o; o += N;
    float* dinv_out = (float*)(ws_i + o); o += N;
    float* dinv_in  = (float*)(ws_i + o); o += N;
    int* bsum = ws_i + o; o += 256;
    o = (o + 1) & ~(size_t)1;                  // int2 alignment
    int2* sorted = (int2*)(ws_i + o); o += 2 * (size_t)E;
    float* agg1 = (float*)(ws_i + o); o += (size_t)N * F0;
    float* x2   = (float*)(ws_i + o); o += (size_t)N * F2;

    hipMemsetAsync(cnt_src, 0, (size_t)2 * N * sizeof(int), stream);

    k_hist<<<(E + 255) / 256, 256, 0, stream>>>(src, dst, cnt_src, cnt_dst, E);
    k_finalize_deg<<<(N + 255) / 256, 256, 0, stream>>>(cnt_src, cnt_dst, dinv_out, dinv_in, N);

    const int nb = (N + SC_E - 1) / SC_E;      // 128
    k_scan_local<<<nb, SC_T, 0, stream>>>(cnt_dst, rowptr, bsum, N);
    k_scan_blocks<<<1, 256, 0, stream>>>(bsum, nb);
    k_scan_add<<<nb, SC_T, 0, stream>>>(rowptr, bsum, cursor, N, (int)E);
    k_fill<<<(E + 255) / 256, 256, 0, stream>>>(src, dst, we, cursor, sorted, E);

    k_gather1<<<(N * 64 + 255) / 256, 256, 0, stream>>>(
        feats, rowptr, sorted, dinv_out, dinv_in, agg1, N);

    k_fused2<<<N / BM, 256, 0, stream>>>(agg1, dinv_out, W1, W2, x2);

    k_gather2_pool<<<G, 256, 0, stream>>>(x2, rowptr, sorted, dinv_in, Wlin, Wcls, out);
}